// Round 10
// baseline (386.004 us; speedup 1.0000x reference)
//
#include <hip/hip_runtime.h>
#include <math.h>

#define N_NODES 100000
#define N_EDGES 1600000
#define DIM 32
#define N_GROUPS 64
#define BN_EPS 1e-5f

#define BIN_NODES 128
#define NBINS ((N_NODES + BIN_NODES - 1) / BIN_NODES)   // 782
#define EPB_HIST 2048
#define HIST_BLOCKS ((N_EDGES + EPB_HIST - 1) / EPB_HIST)  // 782
#define EPB_SCAT 8192
#define SCAT_SUB (EPB_SCAT / EPB_HIST)                      // 4
#define SCAT_BLOCKS ((N_EDGES + EPB_SCAT - 1) / EPB_SCAT)   // 196
#define CNT_PAD 16   // pad bin counters to 64B to avoid atomic line-sharing

#define CS_BPG 16                                            // bins per colsum block (one 64B line)
#define CS_BLOCKS ((NBINS + CS_BPG - 1) / CS_BPG)            // 49

#define HLS 40    // hl row stride in shorts (80 B): 16B-aligned b128, worst 2-way banks

typedef __attribute__((ext_vector_type(8))) short short8;   // 8 bf16 (4 VGPRs)
typedef __attribute__((ext_vector_type(4))) float f32x4;
typedef __attribute__((ext_vector_type(4))) unsigned u32x4;

// ---- monotone float<->uint encoding for atomic max on floats ----
__device__ __forceinline__ unsigned enc_f32(float f) {
    unsigned u = __float_as_uint(f);
    return (u & 0x80000000u) ? ~u : (u | 0x80000000u);
}
__device__ __forceinline__ float dec_f32(unsigned u) {
    return (u & 0x80000000u) ? __uint_as_float(u & 0x7FFFFFFFu) : __uint_as_float(~u);
}
// fp32 -> bf16 bits (RNE)
__device__ __forceinline__ unsigned short f2bf(float f) {
    unsigned u = __float_as_uint(f);
    u += 0x7FFFu + ((u >> 16) & 1u);
    return (unsigned short)(u >> 16);
}

// ===== merged fold + zero-rows + bin histogram (NO global atomics, r9) =====
__global__ __launch_bounds__(256) void foldhist_kernel(
        const float* __restrict__ lin_W, const float* __restrict__ lin_b,
        const float* __restrict__ lin_gamma, const float* __restrict__ lin_beta,
        const float* __restrict__ lin_mean, const float* __restrict__ lin_var,
        const float* __restrict__ conv_W, const float* __restrict__ conv_b,
        const float* __restrict__ conv_gamma, const float* __restrict__ conv_beta,
        const float* __restrict__ conv_mean, const float* __restrict__ conv_var,
        float* __restrict__ shf, unsigned short* __restrict__ Wfb,
        unsigned short* __restrict__ x0b, unsigned short* __restrict__ xbufb,
        const int* __restrict__ dst, int* __restrict__ blockcnt)
{
    __shared__ int cnt[NBINS];
    int bid = blockIdx.x;
    int t = threadIdx.x;
    if (bid >= 6) {
        // ---- hist role ----
        int hb = bid - 6;
        for (int b = t; b < NBINS; b += 256) cnt[b] = 0;
        __syncthreads();
        int base = hb * EPB_HIST;
        for (int i = 0; i < EPB_HIST / 256; ++i) {
            int e = base + i * 256 + t;
            if (e < N_EDGES) atomicAdd(&cnt[dst[e] >> 7], 1);
        }
        __syncthreads();
        for (int b = t; b < NBINS; b += 256)
            blockcnt[(size_t)hb * NBINS + b] = cnt[b];
        return;
    }
    if (bid == 5) {
        if (t < DIM) {
            x0b[(size_t)N_NODES * DIM + t] = 0;
            xbufb[(size_t)N_NODES * DIM + t] = 0;
        }
        return;
    }
    // ---- fold role: layer bid (0..2 lin, 3..4 conv) ----
    const float *W, *b, *gm, *bt, *mn, *vr;
    if (bid < 3) {
        W = lin_W + bid * DIM * DIM; b = lin_b + bid * DIM; gm = lin_gamma + bid * DIM;
        bt = lin_beta + bid * DIM;   mn = lin_mean + bid * DIM; vr = lin_var + bid * DIM;
    } else {
        int c = bid - 3;
        W = conv_W + c * DIM * DIM; b = conv_b + c * DIM; gm = conv_gamma + c * DIM;
        bt = conv_beta + c * DIM;   mn = conv_mean + c * DIM; vr = conv_var + c * DIM;
    }
    for (int idx = t; idx < DIM * DIM; idx += 256) {
        int j = idx & (DIM - 1);
        float scale = gm[j] / sqrtf(vr[j] + BN_EPS);
        Wfb[bid * DIM * DIM + idx] = f2bf(W[idx] * scale);
    }
    if (t < DIM) {
        float scale = gm[t] / sqrtf(vr[t] + BN_EPS);
        shf[bid * DIM + t] = (b[t] - mn[t]) * scale + bt[t];
    }
}

// ===== column-sum of blockcnt + ticket scan (r9 proven) =====
__global__ __launch_bounds__(256) void colsum_scan_kernel(
        const int* __restrict__ blockcnt,
        int* __restrict__ bincnt,
        int* __restrict__ binoff, int* __restrict__ bincur,
        int* __restrict__ done)
{
    __shared__ int sums[16][CS_BPG];
    __shared__ int sscan[256];
    __shared__ int tick;
    int t = threadIdx.x;
    int g = blockIdx.x;
    int bl = t & 15;            // bin within group
    int h0 = t >> 4;            // row phase 0..15
    int b = g * CS_BPG + bl;
    int s = 0;
    if (b < NBINS) {
        for (int hb = h0; hb < HIST_BLOCKS; hb += 16)
            s += blockcnt[(size_t)hb * NBINS + b];
    }
    sums[h0][bl] = s;
    __syncthreads();
    if (t < CS_BPG && (g * CS_BPG + t) < NBINS) {
        int tot = 0;
#pragma unroll
        for (int h = 0; h < 16; ++h) tot += sums[h][t];
        atomicExch(&bincnt[(g * CS_BPG + t) * CNT_PAD], tot);
    }
    __threadfence();
    __syncthreads();
    if (t == 0) tick = atomicAdd(done, 1);
    __syncthreads();
    if (tick == (int)gridDim.x - 1) {
        int i0 = t * 4;
        int c0 = (i0 + 0 < NBINS) ? atomicAdd(&bincnt[(i0 + 0) * CNT_PAD], 0) : 0;
        int c1 = (i0 + 1 < NBINS) ? atomicAdd(&bincnt[(i0 + 1) * CNT_PAD], 0) : 0;
        int c2 = (i0 + 2 < NBINS) ? atomicAdd(&bincnt[(i0 + 2) * CNT_PAD], 0) : 0;
        int c3 = (i0 + 3 < NBINS) ? atomicAdd(&bincnt[(i0 + 3) * CNT_PAD], 0) : 0;
        int local = c0 + c1 + c2 + c3;
        sscan[t] = local;
        __syncthreads();
        for (int off = 1; off < 256; off <<= 1) {
            int u = (t >= off) ? sscan[t - off] : 0;
            __syncthreads();
            sscan[t] += u;
            __syncthreads();
        }
        int run = sscan[t] - local;
        if (i0 + 0 < NBINS) { binoff[i0 + 0] = run; bincur[(i0 + 0) * CNT_PAD] = run; run += c0; }
        if (i0 + 1 < NBINS) { binoff[i0 + 1] = run; bincur[(i0 + 1) * CNT_PAD] = run; run += c1; }
        if (i0 + 2 < NBINS) { binoff[i0 + 2] = run; bincur[(i0 + 2) * CNT_PAD] = run; run += c2; }
        if (i0 + 3 < NBINS) { binoff[i0 + 3] = run; bincur[(i0 + 3) * CNT_PAD] = run; run += c3; }
        if (t == 0) binoff[NBINS] = N_EDGES;
    }
}

// ===== merged binscatter (512 thr, coarse chunks) + layer-0 lin MLP =====
__global__ __launch_bounds__(512) void scatter_linz_kernel(
        const int* __restrict__ src, const int* __restrict__ dst,
        int* __restrict__ bincur, unsigned* __restrict__ binbuf,
        const int* __restrict__ blockcnt,
        const float* __restrict__ x0, unsigned short* __restrict__ x0b,
        const unsigned short* __restrict__ Wb, const float* __restrict__ shfv,
        const int* __restrict__ batch, const float* __restrict__ lw_ptr,
        float* __restrict__ Z, unsigned* __restrict__ segmax)
{
    __shared__ int smem[NBINS];          // scatter: pos[NBINS]; linZ: segloc[256]
    int t = threadIdx.x;

    if (blockIdx.x < SCAT_BLOCKS) {
        // ---------------- scatter role ----------------
        int* pos = smem;
        for (int b = t; b < NBINS; b += 512) {
            int c = 0;
#pragma unroll
            for (int k = 0; k < SCAT_SUB; ++k) {
                int r = blockIdx.x * SCAT_SUB + k;
                if (r < HIST_BLOCKS)
                    c += blockcnt[(size_t)r * NBINS + b];
            }
            pos[b] = (c > 0) ? atomicAdd(&bincur[b * CNT_PAD], c) : 0;
        }
        __syncthreads();
        int base = blockIdx.x * EPB_SCAT;
        for (int i = 0; i < EPB_SCAT / 512; ++i) {
            int e = base + i * 512 + t;
            if (e < N_EDGES) {
                int d = dst[e];
                int bin = d >> 7;
                int p = atomicAdd(&pos[bin], 1);
                binbuf[p] = ((unsigned)(d & 127) << 17) | (unsigned)src[e];
            }
        }
        return;
    }

    // ---------------- linZ (layer 0) role: 128 nodes, 8 tile-waves ----------------
    unsigned* segloc = (unsigned*)smem;
    if (t < 8 * DIM) segloc[t] = 0;

    int wv = t >> 6, lane = t & 63;
    int m = lane & 15, kg = lane >> 4;

    short8 b0, b1;
#pragma unroll
    for (int j = 0; j < 8; ++j) {
        int k = kg * 8 + j;
        b0[j] = (short)Wb[k * DIM + m];
        b1[j] = (short)Wb[k * DIM + 16 + m];
    }
    float sh0 = shfv[m], sh1 = shfv[m + 16];
    float lw = lw_ptr[0];
    int blk0 = (blockIdx.x - SCAT_BLOCKS) * 128;
    int gfirst = batch[blk0];
    int row0 = blk0 + wv * 16;
    __syncthreads();

    if (row0 < N_NODES) {
        const float* rp = x0 + (size_t)(row0 + m) * DIM + kg * 8;
        f32x4 v0 = *(const f32x4*)rp;
        f32x4 v1 = *(const f32x4*)(rp + 4);
        short8 a;
        a[0] = (short)f2bf(v0[0]); a[1] = (short)f2bf(v0[1]);
        a[2] = (short)f2bf(v0[2]); a[3] = (short)f2bf(v0[3]);
        a[4] = (short)f2bf(v1[0]); a[5] = (short)f2bf(v1[1]);
        a[6] = (short)f2bf(v1[2]); a[7] = (short)f2bf(v1[3]);
        *(short8*)(x0b + (size_t)(row0 + m) * DIM + kg * 8) = a;   // gin1 gathers it

        f32x4 d0 = {0.f, 0.f, 0.f, 0.f}, d1 = {0.f, 0.f, 0.f, 0.f};
        d0 = __builtin_amdgcn_mfma_f32_16x16x32_bf16(a, b0, d0, 0, 0, 0);
        d1 = __builtin_amdgcn_mfma_f32_16x16x32_bf16(a, b1, d1, 0, 0, 0);
#pragma unroll
        for (int r = 0; r < 4; ++r) {
            int row = row0 + kg * 4 + r;
            float a0 = d0[r] + sh0;
            float a1 = d1[r] + sh1;
            float z0 = a0 > 0.f ? a0 : expm1f(a0);
            float z1 = a1 > 0.f ? a1 : expm1f(a1);
            size_t zi = (size_t)row * DIM;
            Z[zi + m] = lw * z0;
            Z[zi + 16 + m] = lw * z1;
            int g = batch[row];
            int go = g - gfirst;
            if (go < 8) {
                atomicMax(&segloc[go * DIM + m], enc_f32(z0));
                atomicMax(&segloc[go * DIM + 16 + m], enc_f32(z1));
            } else {
                atomicMax(&segmax[g * DIM + m], enc_f32(z0));
                atomicMax(&segmax[g * DIM + 16 + m], enc_f32(z1));
            }
        }
    }
    __syncthreads();
    if (t < 8 * DIM) {
        unsigned v = segloc[t];
        if (v) atomicMax(&segmax[(gfirst + (t >> 5)) * DIM + (t & 31)], v);
    }
}

// ===== fused [binsort +] GIN layer, 512 thr / 128 nodes (one bin) per block.
// do_sort: counting-sort this bin's edges into esrc/nodeptr first (beg/deg kept
// in LDS — avoids the cross-block nodeptr[+1] hazard), then run the gather/MFMA
// phase; esrc read-back is same-block L2-hot (write drained by __syncthreads,
// range exclusive to this block). Layer 2 runs with do_sort=0 on global CSR.
// Last block of layer 2 (outv != null) folds the 3 segmax buffers into out via
// the ticket pattern (r8/r9 proven), reading via atomicAdd(p,0) for coherence.
#define GIN_FETCH4(I0, A)                                                       \
  {                                                                             \
    _Pragma("unroll")                                                           \
    for (int q_ = 0; q_ < 4; ++q_) {                                            \
      int ii_ = (I0) + q_;                                                      \
      int ei_ = beg + ii_;                                                      \
      ei_ = ei_ < (N_EDGES - 1) ? ei_ : (N_EDGES - 1);                          \
      int s_ = esrc[ei_];                                                       \
      s_ = (ii_ < deg) ? s_ : N_NODES;                                          \
      A[q_] = *(const short8*)(xb + (size_t)s_ * DIM + kg8);                    \
    }                                                                           \
  }

#define GIN_MFMA4(A)                                                            \
  {                                                                             \
    _Pragma("unroll")                                                           \
    for (int q_ = 0; q_ < 4; ++q_) {                                            \
      d0[q_] = __builtin_amdgcn_mfma_f32_16x16x32_bf16(A[q_], bc0, d0[q_], 0, 0, 0); \
      d1[q_] = __builtin_amdgcn_mfma_f32_16x16x32_bf16(A[q_], bc1, d1[q_], 0, 0, 0); \
    }                                                                           \
  }

__global__ __launch_bounds__(512) void gin_fused_kernel(
        const unsigned short* __restrict__ xb,    // [N+1,32] bf16 layer input (row N = zeros)
        const unsigned* __restrict__ binbuf,      // bin-grouped packed edges (sort input)
        const int* __restrict__ binoff,           // [NBINS+1]
        int* __restrict__ esrc,                   // node-grouped src ids (out when sorting)
        int* __restrict__ nodeptr,                // [>=N+1] (out when sorting)
        int do_sort,
        const unsigned short* __restrict__ Wcb, const float* __restrict__ shc,
        const unsigned short* __restrict__ Wlb, const float* __restrict__ shl,
        const int* __restrict__ batch, const float* __restrict__ lw_ptr,
        unsigned short* __restrict__ xnextb,      // bf16 out (may be null)
        float* __restrict__ xoutf,                // fp32 conv out (may be null)
        float* __restrict__ Z,                    // [N,32] +=
        unsigned* __restrict__ segmax,            // this layer's [G,32] encoded
        unsigned* __restrict__ sm0, unsigned* __restrict__ sm1,
        float* __restrict__ outv, int* __restrict__ done)
{
    __shared__ __align__(16) unsigned short hl[8][16 * HLS];   // 10 KB
    __shared__ unsigned segloc[8 * DIM];                       // 1 KB
    __shared__ int cnt[BIN_NODES];
    __shared__ int sc[BIN_NODES];
    __shared__ int begL[BIN_NODES];
    __shared__ int degL[BIN_NODES];
    __shared__ int lastt;
    int t = threadIdx.x;
    if (t < 8 * DIM) segloc[t] = 0;

    int bin = blockIdx.x;

    if (do_sort) {
        int sbeg = binoff[bin], send = binoff[bin + 1];
        if (t < BIN_NODES) cnt[t] = 0;
        __syncthreads();
        for (int e = sbeg + t; e < send; e += 512)
            atomicAdd(&cnt[binbuf[e] >> 17], 1);
        __syncthreads();
        int v = (t < BIN_NODES) ? cnt[t] : 0;
        if (t < BIN_NODES) sc[t] = v;
        __syncthreads();
        for (int off = 1; off < BIN_NODES; off <<= 1) {
            int u = (t < BIN_NODES && t >= off) ? sc[t - off] : 0;
            __syncthreads();
            if (t < BIN_NODES) sc[t] += u;
            __syncthreads();
        }
        if (t < BIN_NODES) {
            int excl = sc[t] - v;
            cnt[t] = excl;
            begL[t] = sbeg + excl;
            degL[t] = v;
            nodeptr[bin * BIN_NODES + t] = sbeg + excl;   // layer 2 needs it
        }
        __syncthreads();
        for (int e = sbeg + t; e < send; e += 512) {
            unsigned pe = binbuf[e];
            int dl = (int)(pe >> 17);
            int p = atomicAdd(&cnt[dl], 1);
            esrc[sbeg + p] = (int)(pe & 0x1FFFFu);
        }
    }
    __syncthreads();   // esrc writes drained (vmcnt); segloc init visible

    int wv = t >> 6, lane = t & 63;
    int m = lane & 15, kg = lane >> 4;
    int kg8 = kg * 8;

    // B fragments: B[k=kg*8+j][n=m]
    short8 bc0, bc1, bl0, bl1;
#pragma unroll
    for (int j = 0; j < 8; ++j) {
        int k = kg8 + j;
        bc0[j] = (short)Wcb[k * DIM + m];
        bc1[j] = (short)Wcb[k * DIM + 16 + m];
        bl0[j] = (short)Wlb[k * DIM + m];
        bl1[j] = (short)Wlb[k * DIM + 16 + m];
    }
    float shc0 = shc[m], shc1 = shc[m + 16];
    float shl0 = shl[m], shl1 = shl[m + 16];
    float lw = lw_ptr[0];
    int blk0 = bin * BIN_NODES;
    int gfirst = batch[blk0];            // first node of bin, always real
    int row0 = blk0 + wv * 16;

    if (row0 < N_NODES) {                 // N%16==0: whole tile valid or wave idle
        int li = wv * 16 + m;             // local node index in bin
        int beg, deg;
        if (do_sort) {
            beg = begL[li];
            deg = degL[li];
        } else {
            beg = nodeptr[row0 + m];
            deg = nodeptr[row0 + m + 1] - beg;
        }
        int md = deg;
#pragma unroll
        for (int off = 1; off < 16; off <<= 1)
            md = max(md, __shfl_xor(md, off, 64));   // max over the 16 rows

        // self row seeds stream 0
        short8 aS = *(const short8*)(xb + (size_t)(row0 + m) * DIM + kg8);
        f32x4 d0[4], d1[4];
#pragma unroll
        for (int q = 0; q < 4; ++q) {
            d0[q] = (f32x4){0.f, 0.f, 0.f, 0.f};
            d1[q] = (f32x4){0.f, 0.f, 0.f, 0.f};
        }
        d0[0] = __builtin_amdgcn_mfma_f32_16x16x32_bf16(aS, bc0, d0[0], 0, 0, 0);
        d1[0] = __builtin_amdgcn_mfma_f32_16x16x32_bf16(aS, bc1, d1[0], 0, 0, 0);

        int B = (md + 3) >> 2;            // number of 4-edge blocks
        if (B > 0) {
            short8 aA[4], aB[4];
            GIN_FETCH4(0, aA);
            int k = 1;
            for (; k + 1 < B; k += 2) {   // ping-pong: fetch next while MFMAing current
                GIN_FETCH4(4 * k, aB);
                GIN_MFMA4(aA);
                GIN_FETCH4(4 * (k + 1), aA);
                GIN_MFMA4(aB);
            }
            if (k < B) {
                GIN_FETCH4(4 * k, aB);
                GIN_MFMA4(aA);
                GIN_MFMA4(aB);
            } else {
                GIN_MFMA4(aA);
            }
        }

        // conv epilogue: D-layout row = row0 + kg*4 + r, cols m / m+16
        float hp0[4], hp1[4];
#pragma unroll
        for (int r = 0; r < 4; ++r) {
            float a0 = d0[0][r] + d0[1][r] + d0[2][r] + d0[3][r] + shc0;
            float a1 = d1[0][r] + d1[1][r] + d1[2][r] + d1[3][r] + shc1;
            hp0[r] = a0 > 0.f ? a0 : expm1f(a0);
            hp1[r] = a1 > 0.f ? a1 : expm1f(a1);
        }
#pragma unroll
        for (int r = 0; r < 4; ++r) {     // D-layout -> row-major bf16 tile (same-wave LDS)
            hl[wv][(kg * 4 + r) * HLS + m] = f2bf(hp0[r]);
            hl[wv][(kg * 4 + r) * HLS + 16 + m] = f2bf(hp1[r]);
        }
        if (xoutf) {
#pragma unroll
            for (int r = 0; r < 4; ++r) {
                int row = row0 + kg * 4 + r;
                xoutf[(size_t)row * DIM + m] = hp0[r];
                xoutf[(size_t)row * DIM + 16 + m] = hp1[r];
            }
        }
        if (xnextb) {                     // coalesced bf16 out from LDS
            int ii = lane >> 2, q = lane & 3;
            u32x4 pk = *(const u32x4*)&hl[wv][ii * HLS + q * 8];
            *(u32x4*)(xnextb + (size_t)(row0 + ii) * DIM + q * 8) = pk;
        }

        // lin MLP via MFMA
        short8 a2 = *(const short8*)&hl[wv][m * HLS + kg8];
        f32x4 e0 = {0.f, 0.f, 0.f, 0.f}, e1 = {0.f, 0.f, 0.f, 0.f};
        e0 = __builtin_amdgcn_mfma_f32_16x16x32_bf16(a2, bl0, e0, 0, 0, 0);
        e1 = __builtin_amdgcn_mfma_f32_16x16x32_bf16(a2, bl1, e1, 0, 0, 0);
#pragma unroll
        for (int r = 0; r < 4; ++r) {
            int row = row0 + kg * 4 + r;
            float a0 = e0[r] + shl0, a1 = e1[r] + shl1;
            float z0 = a0 > 0.f ? a0 : expm1f(a0);
            float z1 = a1 > 0.f ? a1 : expm1f(a1);
            float zw0 = lw * z0, zw1 = lw * z1;
            size_t zi = (size_t)row * DIM;
            Z[zi + m] += zw0;
            Z[zi + 16 + m] += zw1;
            int g = batch[row];
            int go = g - gfirst;
            if (go < 8) {
                atomicMax(&segloc[go * DIM + m], enc_f32(zw0));
                atomicMax(&segloc[go * DIM + 16 + m], enc_f32(zw1));
            } else {
                atomicMax(&segmax[g * DIM + m], enc_f32(zw0));
                atomicMax(&segmax[g * DIM + 16 + m], enc_f32(zw1));
            }
        }
    }
    __syncthreads();
    if (t < 8 * DIM) {
        unsigned v = segloc[t];
        if (v) atomicMax(&segmax[(gfirst + (t >> 5)) * DIM + (t & 31)], v);
    }

    // ---- merged add_out (layer 2 only): last block sums the 3 segmax buffers ----
    if (outv) {
        __threadfence();
        __syncthreads();                  // this block's segmax atomics drained
        if (t == 0) lastt = atomicAdd(done, 1);
        __syncthreads();
        if (lastt == (int)gridDim.x - 1) {
            for (int i = t; i < N_GROUPS * DIM; i += 512) {
                unsigned a = atomicAdd(&sm0[i], 0u);      // coherent-point reads
                unsigned b = atomicAdd(&sm1[i], 0u);
                unsigned c = atomicAdd(&segmax[i], 0u);
                outv[i] = dec_f32(a) + dec_f32(b) + dec_f32(c);
            }
        }
    }
}

extern "C" void kernel_launch(void* const* d_in, const int* in_sizes, int n_in,
                              void* d_out, int out_size, void* d_ws, size_t ws_size,
                              hipStream_t stream) {
    const float* x0        = (const float*)d_in[0];
    const int*   ei        = (const int*)d_in[1];     // (2,E): row0=src, row1=dst
    const int*   batch     = (const int*)d_in[2];
    const float* lw        = (const float*)d_in[3];
    const float* lin_W     = (const float*)d_in[4];
    const float* lin_b     = (const float*)d_in[5];
    const float* lin_gamma = (const float*)d_in[6];
    const float* lin_beta  = (const float*)d_in[7];
    const float* lin_mean  = (const float*)d_in[8];
    const float* lin_var   = (const float*)d_in[9];
    const float* conv_W    = (const float*)d_in[10];
    const float* conv_b    = (const float*)d_in[11];
    const float* conv_gamma= (const float*)d_in[12];
    const float* conv_beta = (const float*)d_in[13];
    const float* conv_mean = (const float*)d_in[14];
    const float* conv_var  = (const float*)d_in[15];

    float* out  = (float*)d_out;                 // [G*32]
    float* Z    = out + N_GROUPS * DIM;          // [N*32]
    float* xout = Z + (size_t)N_NODES * DIM;     // [N*32] final x (fp32 conv out, layer 2)

    char* p = (char*)d_ws;
    unsigned short* x0b     = (unsigned short*)p; p += ((size_t)N_NODES * DIM + 8192) * sizeof(unsigned short);
    unsigned short* xbufb   = (unsigned short*)p; p += ((size_t)N_NODES * DIM + 8192) * sizeof(unsigned short);
    unsigned*       binbuf  = (unsigned*)p;       p += (size_t)N_EDGES * sizeof(unsigned);
    int*            esrc    = (int*)p;            p += (size_t)N_EDGES * sizeof(int);
    int*            nodeptr = (int*)p;            p += (NBINS * BIN_NODES + 1) * sizeof(int);
    unsigned*       segmx   = (unsigned*)p;       p += 3 * N_GROUPS * DIM * sizeof(unsigned);
    int*            bincnt  = (int*)p;            p += NBINS * CNT_PAD * sizeof(int);   // contiguous after segmx
    int*            donec   = (int*)p;            p += 16 * sizeof(int);                // ticket counters (memset'd)
    int*            binoff  = (int*)p;            p += (NBINS + 1) * sizeof(int);
    int*            bincur  = (int*)p;            p += NBINS * CNT_PAD * sizeof(int);
    float*          shf     = (float*)p;          p += 5 * DIM * sizeof(float);
    unsigned short* Wfb     = (unsigned short*)p; p += 5 * DIM * DIM * sizeof(unsigned short);

    // blockcnt (HIST_BLOCKS x NBINS ints = 2.45 MB) aliases xbufb: consumed by
    // colsum+scatter before gin-layer-1 writes xbufb; fold's pad-zeroing only
    // touches xbufb bytes past 6.4 MB.
    int* blockcnt = (int*)xbufb;

    const int* src = ei;
    const int* dst = ei + N_EDGES;

    // zero segmx (3 buffers) + bincnt + tickets in one async memset (adjacent)
    (void)hipMemsetAsync(segmx, 0,
                         (3 * N_GROUPS * DIM + NBINS * CNT_PAD + 16) * sizeof(unsigned), stream);

    foldhist_kernel<<<6 + HIST_BLOCKS, 256, 0, stream>>>(
        lin_W, lin_b, lin_gamma, lin_beta, lin_mean, lin_var,
        conv_W, conv_b, conv_gamma, conv_beta, conv_mean, conv_var,
        shf, Wfb, x0b, xbufb, dst, blockcnt);

    colsum_scan_kernel<<<CS_BLOCKS, 256, 0, stream>>>(blockcnt, bincnt,
                                                      binoff, bincur, donec);

    scatter_linz_kernel<<<SCAT_BLOCKS + NBINS, 512, 0, stream>>>(
        src, dst, bincur, binbuf, blockcnt,
        x0, x0b, Wfb, shf, batch, lw, Z, segmx);

    // ---- layer 1: fused binsort + GIN ----
    gin_fused_kernel<<<NBINS, 512, 0, stream>>>(x0b, binbuf, binoff, esrc, nodeptr, 1,
                                                Wfb + 3 * DIM * DIM, shf + 3 * DIM,
                                                Wfb + 1 * DIM * DIM, shf + 1 * DIM,
                                                batch, lw + 1,
                                                xbufb, (float*)nullptr, Z,
                                                segmx + N_GROUPS * DIM,
                                                (unsigned*)nullptr, (unsigned*)nullptr,
                                                (float*)nullptr, (int*)nullptr);

    // ---- layer 2: GIN on global CSR; last block folds segmax sums into out ----
    gin_fused_kernel<<<NBINS, 512, 0, stream>>>(xbufb, binbuf, binoff, esrc, nodeptr, 0,
                                                Wfb + 4 * DIM * DIM, shf + 4 * DIM,
                                                Wfb + 2 * DIM * DIM, shf + 2 * DIM,
                                                batch, lw + 2,
                                                (unsigned short*)nullptr, xout, Z,
                                                segmx + 2 * N_GROUPS * DIM,
                                                segmx, segmx + N_GROUPS * DIM,
                                                out, donec + 1);
}

// Round 12
// 227.685 us; speedup vs baseline: 1.6953x; 1.6953x over previous
//
#include <hip/hip_runtime.h>
#include <math.h>

#define N_NODES 100000
#define N_EDGES 1600000
#define DIM 32
#define N_GROUPS 64
#define BN_EPS 1e-5f

#define BIN_NODES 128
#define NBINS ((N_NODES + BIN_NODES - 1) / BIN_NODES)   // 782
#define EPB_HIST 2048
#define HIST_BLOCKS ((N_EDGES + EPB_HIST - 1) / EPB_HIST)  // 782
#define EPB_SCAT 8192
#define SCAT_SUB (EPB_SCAT / EPB_HIST)                      // 4
#define SCAT_BLOCKS ((N_EDGES + EPB_SCAT - 1) / EPB_SCAT)   // 196
#define GF2_BLOCKS ((N_NODES + 127) / 128)                  // 782 (128-node linZ blocks)
#define CNT_PAD 16   // pad bin counters to 64B to avoid atomic line-sharing

#define CS_BPG 16                                            // bins per colsum block (one 64B line)
#define CS_BLOCKS ((NBINS + CS_BPG - 1) / CS_BPG)            // 49

#define HLS 40    // hl row stride in shorts (80 B): 16B-aligned b128, worst 2-way banks

typedef __attribute__((ext_vector_type(8))) short short8;   // 8 bf16 (4 VGPRs)
typedef __attribute__((ext_vector_type(4))) float f32x4;
typedef __attribute__((ext_vector_type(4))) unsigned u32x4;

// ---- monotone float<->uint encoding for atomic max on floats ----
__device__ __forceinline__ unsigned enc_f32(float f) {
    unsigned u = __float_as_uint(f);
    return (u & 0x80000000u) ? ~u : (u | 0x80000000u);
}
__device__ __forceinline__ float dec_f32(unsigned u) {
    return (u & 0x80000000u) ? __uint_as_float(u & 0x7FFFFFFFu) : __uint_as_float(~u);
}
// fp32 -> bf16 bits (RNE)
__device__ __forceinline__ unsigned short f2bf(float f) {
    unsigned u = __float_as_uint(f);
    u += 0x7FFFu + ((u >> 16) & 1u);
    return (unsigned short)(u >> 16);
}

// ===== merged fold + zero-rows + bin histogram (NO global atomics, r9) =====
__global__ __launch_bounds__(256) void foldhist_kernel(
        const float* __restrict__ lin_W, const float* __restrict__ lin_b,
        const float* __restrict__ lin_gamma, const float* __restrict__ lin_beta,
        const float* __restrict__ lin_mean, const float* __restrict__ lin_var,
        const float* __restrict__ conv_W, const float* __restrict__ conv_b,
        const float* __restrict__ conv_gamma, const float* __restrict__ conv_beta,
        const float* __restrict__ conv_mean, const float* __restrict__ conv_var,
        float* __restrict__ shf, unsigned short* __restrict__ Wfb,
        unsigned short* __restrict__ x0b, unsigned short* __restrict__ xbufb,
        const int* __restrict__ dst, int* __restrict__ blockcnt)
{
    __shared__ int cnt[NBINS];
    int bid = blockIdx.x;
    int t = threadIdx.x;
    if (bid >= 6) {
        // ---- hist role ----
        int hb = bid - 6;
        for (int b = t; b < NBINS; b += 256) cnt[b] = 0;
        __syncthreads();
        int base = hb * EPB_HIST;
        for (int i = 0; i < EPB_HIST / 256; ++i) {
            int e = base + i * 256 + t;
            if (e < N_EDGES) atomicAdd(&cnt[dst[e] >> 7], 1);
        }
        __syncthreads();
        for (int b = t; b < NBINS; b += 256)
            blockcnt[(size_t)hb * NBINS + b] = cnt[b];
        return;
    }
    if (bid == 5) {
        if (t < DIM) {
            x0b[(size_t)N_NODES * DIM + t] = 0;
            xbufb[(size_t)N_NODES * DIM + t] = 0;
        }
        return;
    }
    // ---- fold role: layer bid (0..2 lin, 3..4 conv) ----
    const float *W, *b, *gm, *bt, *mn, *vr;
    if (bid < 3) {
        W = lin_W + bid * DIM * DIM; b = lin_b + bid * DIM; gm = lin_gamma + bid * DIM;
        bt = lin_beta + bid * DIM;   mn = lin_mean + bid * DIM; vr = lin_var + bid * DIM;
    } else {
        int c = bid - 3;
        W = conv_W + c * DIM * DIM; b = conv_b + c * DIM; gm = conv_gamma + c * DIM;
        bt = conv_beta + c * DIM;   mn = conv_mean + c * DIM; vr = conv_var + c * DIM;
    }
    for (int idx = t; idx < DIM * DIM; idx += 256) {
        int j = idx & (DIM - 1);
        float scale = gm[j] / sqrtf(vr[j] + BN_EPS);
        Wfb[bid * DIM * DIM + idx] = f2bf(W[idx] * scale);
    }
    if (t < DIM) {
        float scale = gm[t] / sqrtf(vr[t] + BN_EPS);
        shf[bid * DIM + t] = (b[t] - mn[t]) * scale + bt[t];
    }
}

// ===== column-sum of blockcnt (line-wise, no amplification) + ticket scan =====
__global__ __launch_bounds__(256) void colsum_scan_kernel(
        const int* __restrict__ blockcnt,
        int* __restrict__ bincnt,
        int* __restrict__ binoff, int* __restrict__ bincur,
        int* __restrict__ done)
{
    __shared__ int sums[16][CS_BPG];
    __shared__ int sscan[256];
    __shared__ int tick;
    int t = threadIdx.x;
    int g = blockIdx.x;
    int bl = t & 15;            // bin within group
    int h0 = t >> 4;            // row phase 0..15
    int b = g * CS_BPG + bl;
    int s = 0;
    if (b < NBINS) {
        for (int hb = h0; hb < HIST_BLOCKS; hb += 16)
            s += blockcnt[(size_t)hb * NBINS + b];
    }
    sums[h0][bl] = s;
    __syncthreads();
    if (t < CS_BPG && (g * CS_BPG + t) < NBINS) {
        int tot = 0;
#pragma unroll
        for (int h = 0; h < 16; ++h) tot += sums[h][t];
        atomicExch(&bincnt[(g * CS_BPG + t) * CNT_PAD], tot);
    }
    __threadfence();
    __syncthreads();
    if (t == 0) tick = atomicAdd(done, 1);
    __syncthreads();
    if (tick == (int)gridDim.x - 1) {
        int i0 = t * 4;
        int c0 = (i0 + 0 < NBINS) ? atomicAdd(&bincnt[(i0 + 0) * CNT_PAD], 0) : 0;
        int c1 = (i0 + 1 < NBINS) ? atomicAdd(&bincnt[(i0 + 1) * CNT_PAD], 0) : 0;
        int c2 = (i0 + 2 < NBINS) ? atomicAdd(&bincnt[(i0 + 2) * CNT_PAD], 0) : 0;
        int c3 = (i0 + 3 < NBINS) ? atomicAdd(&bincnt[(i0 + 3) * CNT_PAD], 0) : 0;
        int local = c0 + c1 + c2 + c3;
        sscan[t] = local;
        __syncthreads();
        for (int off = 1; off < 256; off <<= 1) {
            int u = (t >= off) ? sscan[t - off] : 0;
            __syncthreads();
            sscan[t] += u;
            __syncthreads();
        }
        int run = sscan[t] - local;
        if (i0 + 0 < NBINS) { binoff[i0 + 0] = run; bincur[(i0 + 0) * CNT_PAD] = run; run += c0; }
        if (i0 + 1 < NBINS) { binoff[i0 + 1] = run; bincur[(i0 + 1) * CNT_PAD] = run; run += c1; }
        if (i0 + 2 < NBINS) { binoff[i0 + 2] = run; bincur[(i0 + 2) * CNT_PAD] = run; run += c2; }
        if (i0 + 3 < NBINS) { binoff[i0 + 3] = run; bincur[(i0 + 3) * CNT_PAD] = run; run += c3; }
        if (t == 0) binoff[NBINS] = N_EDGES;
    }
}

// ===== merged binscatter (512 thr, coarse chunks) + layer-0 lin MLP =====
__global__ __launch_bounds__(512) void scatter_linz_kernel(
        const int* __restrict__ src, const int* __restrict__ dst,
        int* __restrict__ bincur, unsigned* __restrict__ binbuf,
        const int* __restrict__ blockcnt,
        const float* __restrict__ x0, unsigned short* __restrict__ x0b,
        const unsigned short* __restrict__ Wb, const float* __restrict__ shfv,
        const int* __restrict__ batch, const float* __restrict__ lw_ptr,
        float* __restrict__ Z, unsigned* __restrict__ segmax)
{
    __shared__ int smem[NBINS];          // scatter: pos[NBINS]; linZ: segloc[256]
    int t = threadIdx.x;

    if (blockIdx.x < SCAT_BLOCKS) {
        // ---------------- scatter role ----------------
        int* pos = smem;
        for (int b = t; b < NBINS; b += 512) {
            int c = 0;
#pragma unroll
            for (int k = 0; k < SCAT_SUB; ++k) {
                int r = blockIdx.x * SCAT_SUB + k;
                if (r < HIST_BLOCKS)
                    c += blockcnt[(size_t)r * NBINS + b];
            }
            pos[b] = (c > 0) ? atomicAdd(&bincur[b * CNT_PAD], c) : 0;
        }
        __syncthreads();
        int base = blockIdx.x * EPB_SCAT;
        for (int i = 0; i < EPB_SCAT / 512; ++i) {
            int e = base + i * 512 + t;
            if (e < N_EDGES) {
                int d = dst[e];
                int bin = d >> 7;
                int p = atomicAdd(&pos[bin], 1);
                binbuf[p] = ((unsigned)(d & 127) << 17) | (unsigned)src[e];
            }
        }
        return;
    }

    // ---------------- linZ (layer 0) role: 128 nodes, 8 tile-waves ----------------
    unsigned* segloc = (unsigned*)smem;
    if (t < 8 * DIM) segloc[t] = 0;

    int wv = t >> 6, lane = t & 63;
    int m = lane & 15, kg = lane >> 4;

    short8 b0, b1;
#pragma unroll
    for (int j = 0; j < 8; ++j) {
        int k = kg * 8 + j;
        b0[j] = (short)Wb[k * DIM + m];
        b1[j] = (short)Wb[k * DIM + 16 + m];
    }
    float sh0 = shfv[m], sh1 = shfv[m + 16];
    float lw = lw_ptr[0];
    int blk0 = (blockIdx.x - SCAT_BLOCKS) * 128;
    int gfirst = batch[blk0];
    int row0 = blk0 + wv * 16;
    __syncthreads();

    if (row0 < N_NODES) {
        const float* rp = x0 + (size_t)(row0 + m) * DIM + kg * 8;
        f32x4 v0 = *(const f32x4*)rp;
        f32x4 v1 = *(const f32x4*)(rp + 4);
        short8 a;
        a[0] = (short)f2bf(v0[0]); a[1] = (short)f2bf(v0[1]);
        a[2] = (short)f2bf(v0[2]); a[3] = (short)f2bf(v0[3]);
        a[4] = (short)f2bf(v1[0]); a[5] = (short)f2bf(v1[1]);
        a[6] = (short)f2bf(v1[2]); a[7] = (short)f2bf(v1[3]);
        *(short8*)(x0b + (size_t)(row0 + m) * DIM + kg * 8) = a;   // gin1 gathers it

        f32x4 d0 = {0.f, 0.f, 0.f, 0.f}, d1 = {0.f, 0.f, 0.f, 0.f};
        d0 = __builtin_amdgcn_mfma_f32_16x16x32_bf16(a, b0, d0, 0, 0, 0);
        d1 = __builtin_amdgcn_mfma_f32_16x16x32_bf16(a, b1, d1, 0, 0, 0);
#pragma unroll
        for (int r = 0; r < 4; ++r) {
            int row = row0 + kg * 4 + r;
            float a0 = d0[r] + sh0;
            float a1 = d1[r] + sh1;
            float z0 = a0 > 0.f ? a0 : expm1f(a0);
            float z1 = a1 > 0.f ? a1 : expm1f(a1);
            size_t zi = (size_t)row * DIM;
            Z[zi + m] = lw * z0;
            Z[zi + 16 + m] = lw * z1;
            int g = batch[row];
            int go = g - gfirst;
            if (go < 8) {
                atomicMax(&segloc[go * DIM + m], enc_f32(z0));
                atomicMax(&segloc[go * DIM + 16 + m], enc_f32(z1));
            } else {
                atomicMax(&segmax[g * DIM + m], enc_f32(z0));
                atomicMax(&segmax[g * DIM + 16 + m], enc_f32(z1));
            }
        }
    }
    __syncthreads();
    if (t < 8 * DIM) {
        unsigned v = segloc[t];
        if (v) atomicMax(&segmax[(gfirst + (t >> 5)) * DIM + (t & 31)], v);
    }
}

// counting sort within bin -> exact per-node CSR
__global__ __launch_bounds__(256) void binsort_kernel(const unsigned* __restrict__ binbuf,
                                                      const int* __restrict__ binoff,
                                                      int* __restrict__ esrc,
                                                      int* __restrict__ nodeptr) {
    __shared__ int cnt[BIN_NODES];
    __shared__ int sc[BIN_NODES];
    int t = threadIdx.x;
    int bin = blockIdx.x;
    int beg = binoff[bin], end = binoff[bin + 1];
    if (t < BIN_NODES) cnt[t] = 0;
    __syncthreads();
    for (int e = beg + t; e < end; e += 256)
        atomicAdd(&cnt[binbuf[e] >> 17], 1);
    __syncthreads();
    int v = (t < BIN_NODES) ? cnt[t] : 0;
    if (t < BIN_NODES) sc[t] = v;
    __syncthreads();
    for (int off = 1; off < BIN_NODES; off <<= 1) {
        int u = (t < BIN_NODES && t >= off) ? sc[t - off] : 0;
        __syncthreads();
        if (t < BIN_NODES) sc[t] += u;
        __syncthreads();
    }
    if (t < BIN_NODES) {
        int excl = sc[t] - v;
        cnt[t] = excl;
        nodeptr[bin * BIN_NODES + t] = beg + excl;
    }
    __syncthreads();
    for (int e = beg + t; e < end; e += 256) {
        unsigned pe = binbuf[e];
        int dl = (int)(pe >> 17);
        int p = atomicAdd(&cnt[dl], 1);
        esrc[beg + p] = (int)(pe & 0x1FFFFu);
    }
}

// ===== fused GIN layer (round-5 proven, 256 thr / 64 nodes): MFMA-as-reducer,
// 4 independent gather->MFMA streams, branchless clamped loads, 2-deep
// ping-pong prefetch. DO NOT restructure thread shape — the 45 µs depends on
// this exact 256-thread/64-VGPR codegen keeping 4 gathers in flight (r10).
#define GIN_FETCH4(I0, A)                                                       \
  {                                                                             \
    _Pragma("unroll")                                                           \
    for (int q_ = 0; q_ < 4; ++q_) {                                            \
      int ii_ = (I0) + q_;                                                      \
      int ei_ = beg + ii_;                                                      \
      ei_ = ei_ < (N_EDGES - 1) ? ei_ : (N_EDGES - 1);                          \
      int s_ = esrc[ei_];                                                       \
      s_ = (ii_ < deg) ? s_ : N_NODES;                                          \
      A[q_] = *(const short8*)(xb + (size_t)s_ * DIM + kg8);                    \
    }                                                                           \
  }

#define GIN_MFMA4(A)                                                            \
  {                                                                             \
    _Pragma("unroll")                                                           \
    for (int q_ = 0; q_ < 4; ++q_) {                                            \
      d0[q_] = __builtin_amdgcn_mfma_f32_16x16x32_bf16(A[q_], bc0, d0[q_], 0, 0, 0); \
      d1[q_] = __builtin_amdgcn_mfma_f32_16x16x32_bf16(A[q_], bc1, d1[q_], 0, 0, 0); \
    }                                                                           \
  }

__global__ __launch_bounds__(256) void gin_fused_kernel(
        const unsigned short* __restrict__ xb,    // [N+1,32] bf16 layer input (row N = zeros)
        const int* __restrict__ esrc,             // node-grouped src ids
        const int* __restrict__ nodeptr,          // [>=N+1] monotone
        const unsigned short* __restrict__ Wcb, const float* __restrict__ shc,
        const unsigned short* __restrict__ Wlb, const float* __restrict__ shl,
        const int* __restrict__ batch, const float* __restrict__ lw_ptr,
        unsigned short* __restrict__ xnextb,      // bf16 out (may be null)
        float* __restrict__ xoutf,                // fp32 conv out (may be null)
        float* __restrict__ Z,                    // [N,32] +=
        unsigned* __restrict__ segmax)            // [G,32] encoded
{
    __shared__ __align__(16) unsigned short hl[4][16 * HLS];   // 5 KB
    __shared__ unsigned segloc[8 * DIM];                       // 1 KB
    int t = threadIdx.x;
    segloc[t] = 0;

    int wv = t >> 6, lane = t & 63;
    int m = lane & 15, kg = lane >> 4;
    int kg8 = kg * 8;

    // B fragments: B[k=kg*8+j][n=m]
    short8 bc0, bc1, bl0, bl1;
#pragma unroll
    for (int j = 0; j < 8; ++j) {
        int k = kg8 + j;
        bc0[j] = (short)Wcb[k * DIM + m];
        bc1[j] = (short)Wcb[k * DIM + 16 + m];
        bl0[j] = (short)Wlb[k * DIM + m];
        bl1[j] = (short)Wlb[k * DIM + 16 + m];
    }
    float shc0 = shc[m], shc1 = shc[m + 16];
    float shl0 = shl[m], shl1 = shl[m + 16];
    float lw = lw_ptr[0];
    int blk0 = blockIdx.x * 64;
    int gfirst = batch[blk0 < N_NODES ? blk0 : N_NODES - 1];
    int row0 = blk0 + wv * 16;
    __syncthreads();   // segloc init visible

    if (row0 < N_NODES) {                 // N%16==0: whole tile valid or wave idle
        int beg = nodeptr[row0 + m];
        int deg = nodeptr[row0 + m + 1] - beg;
        int md = deg;
#pragma unroll
        for (int off = 1; off < 16; off <<= 1)
            md = max(md, __shfl_xor(md, off, 64));   // max over the 16 rows

        // self row seeds stream 0
        short8 aS = *(const short8*)(xb + (size_t)(row0 + m) * DIM + kg8);
        f32x4 d0[4], d1[4];
#pragma unroll
        for (int q = 0; q < 4; ++q) {
            d0[q] = (f32x4){0.f, 0.f, 0.f, 0.f};
            d1[q] = (f32x4){0.f, 0.f, 0.f, 0.f};
        }
        d0[0] = __builtin_amdgcn_mfma_f32_16x16x32_bf16(aS, bc0, d0[0], 0, 0, 0);
        d1[0] = __builtin_amdgcn_mfma_f32_16x16x32_bf16(aS, bc1, d1[0], 0, 0, 0);

        int B = (md + 3) >> 2;            // number of 4-edge blocks
        if (B > 0) {
            short8 aA[4], aB[4];
            GIN_FETCH4(0, aA);
            int k = 1;
            for (; k + 1 < B; k += 2) {   // ping-pong: fetch next while MFMAing current
                GIN_FETCH4(4 * k, aB);
                GIN_MFMA4(aA);
                GIN_FETCH4(4 * (k + 1), aA);
                GIN_MFMA4(aB);
            }
            if (k < B) {
                GIN_FETCH4(4 * k, aB);
                GIN_MFMA4(aA);
                GIN_MFMA4(aB);
            } else {
                GIN_MFMA4(aA);
            }
        }

        // conv epilogue: D-layout row = row0 + kg*4 + r, cols m / m+16
        float hp0[4], hp1[4];
#pragma unroll
        for (int r = 0; r < 4; ++r) {
            float a0 = d0[0][r] + d0[1][r] + d0[2][r] + d0[3][r] + shc0;
            float a1 = d1[0][r] + d1[1][r] + d1[2][r] + d1[3][r] + shc1;
            hp0[r] = a0 > 0.f ? a0 : expm1f(a0);
            hp1[r] = a1 > 0.f ? a1 : expm1f(a1);
        }
#pragma unroll
        for (int r = 0; r < 4; ++r) {     // D-layout -> row-major bf16 tile (same-wave LDS)
            hl[wv][(kg * 4 + r) * HLS + m] = f2bf(hp0[r]);
            hl[wv][(kg * 4 + r) * HLS + 16 + m] = f2bf(hp1[r]);
        }
        if (xoutf) {
#pragma unroll
            for (int r = 0; r < 4; ++r) {
                int row = row0 + kg * 4 + r;
                xoutf[(size_t)row * DIM + m] = hp0[r];
                xoutf[(size_t)row * DIM + 16 + m] = hp1[r];
            }
        }
        if (xnextb) {                     // coalesced bf16 out from LDS
            int ii = lane >> 2, q = lane & 3;
            u32x4 pk = *(const u32x4*)&hl[wv][ii * HLS + q * 8];
            *(u32x4*)(xnextb + (size_t)(row0 + ii) * DIM + q * 8) = pk;
        }

        // lin MLP via MFMA
        short8 a2 = *(const short8*)&hl[wv][m * HLS + kg8];
        f32x4 e0 = {0.f, 0.f, 0.f, 0.f}, e1 = {0.f, 0.f, 0.f, 0.f};
        e0 = __builtin_amdgcn_mfma_f32_16x16x32_bf16(a2, bl0, e0, 0, 0, 0);
        e1 = __builtin_amdgcn_mfma_f32_16x16x32_bf16(a2, bl1, e1, 0, 0, 0);
#pragma unroll
        for (int r = 0; r < 4; ++r) {
            int row = row0 + kg * 4 + r;
            float a0 = e0[r] + shl0, a1 = e1[r] + shl1;
            float z0 = a0 > 0.f ? a0 : expm1f(a0);
            float z1 = a1 > 0.f ? a1 : expm1f(a1);
            float zw0 = lw * z0, zw1 = lw * z1;
            size_t zi = (size_t)row * DIM;
            Z[zi + m] += zw0;
            Z[zi + 16 + m] += zw1;
            int g = batch[row];
            int go = g - gfirst;
            if (go < 8) {
                atomicMax(&segloc[go * DIM + m], enc_f32(zw0));
                atomicMax(&segloc[go * DIM + 16 + m], enc_f32(zw1));
            } else {
                atomicMax(&segmax[g * DIM + m], enc_f32(zw0));
                atomicMax(&segmax[g * DIM + 16 + m], enc_f32(zw1));
            }
        }
    }
    __syncthreads();
    unsigned v = segloc[t];
    if (v) atomicMax(&segmax[(gfirst + (t >> 5)) * DIM + (t & 31)], v);
}

// out[g][j] = sum over layers of decode(segmax_l[g][j]) — single final reduction.
__global__ void add_out3_kernel(const unsigned* __restrict__ s0,
                                const unsigned* __restrict__ s1,
                                const unsigned* __restrict__ s2,
                                float* __restrict__ out) {
    int t = blockIdx.x * blockDim.x + threadIdx.x;  // 2048
    out[t] = dec_f32(s0[t]) + dec_f32(s1[t]) + dec_f32(s2[t]);
}

extern "C" void kernel_launch(void* const* d_in, const int* in_sizes, int n_in,
                              void* d_out, int out_size, void* d_ws, size_t ws_size,
                              hipStream_t stream) {
    const float* x0        = (const float*)d_in[0];
    const int*   ei        = (const int*)d_in[1];     // (2,E): row0=src, row1=dst
    const int*   batch     = (const int*)d_in[2];
    const float* lw        = (const float*)d_in[3];
    const float* lin_W     = (const float*)d_in[4];
    const float* lin_b     = (const float*)d_in[5];
    const float* lin_gamma = (const float*)d_in[6];
    const float* lin_beta  = (const float*)d_in[7];
    const float* lin_mean  = (const float*)d_in[8];
    const float* lin_var   = (const float*)d_in[9];
    const float* conv_W    = (const float*)d_in[10];
    const float* conv_b    = (const float*)d_in[11];
    const float* conv_gamma= (const float*)d_in[12];
    const float* conv_beta = (const float*)d_in[13];
    const float* conv_mean = (const float*)d_in[14];
    const float* conv_var  = (const float*)d_in[15];

    float* out  = (float*)d_out;                 // [G*32]
    float* Z    = out + N_GROUPS * DIM;          // [N*32]
    float* xout = Z + (size_t)N_NODES * DIM;     // [N*32] final x (fp32 conv out, layer 2)

    char* p = (char*)d_ws;
    unsigned short* x0b     = (unsigned short*)p; p += ((size_t)N_NODES * DIM + 8192) * sizeof(unsigned short);
    unsigned short* xbufb   = (unsigned short*)p; p += ((size_t)N_NODES * DIM + 8192) * sizeof(unsigned short);
    unsigned*       binbuf  = (unsigned*)p;       p += (size_t)N_EDGES * sizeof(unsigned);
    int*            esrc    = (int*)p;            p += (size_t)N_EDGES * sizeof(int);
    int*            nodeptr = (int*)p;            p += (NBINS * BIN_NODES + 1) * sizeof(int);
    unsigned*       segmx   = (unsigned*)p;       p += 3 * N_GROUPS * DIM * sizeof(unsigned);
    int*            bincnt  = (int*)p;            p += NBINS * CNT_PAD * sizeof(int);   // contiguous after segmx
    int*            donec   = (int*)p;            p += 16 * sizeof(int);                // ticket counter (memset'd)
    int*            binoff  = (int*)p;            p += (NBINS + 1) * sizeof(int);
    int*            bincur  = (int*)p;            p += NBINS * CNT_PAD * sizeof(int);
    float*          shf     = (float*)p;          p += 5 * DIM * sizeof(float);
    unsigned short* Wfb     = (unsigned short*)p; p += 5 * DIM * DIM * sizeof(unsigned short);

    // blockcnt (HIST_BLOCKS x NBINS ints = 2.45 MB) aliases xbufb: consumed by
    // colsum+scatter before gin-layer-1 writes xbufb; fold's pad-zeroing only
    // touches xbufb bytes past 6.4 MB.
    int* blockcnt = (int*)xbufb;

    const int* src = ei;
    const int* dst = ei + N_EDGES;

    const int gf_blocks = (N_NODES + 63) / 64;   // 1563

    // zero segmx (3 buffers) + bincnt + ticket in one async memset (adjacent)
    (void)hipMemsetAsync(segmx, 0,
                         (3 * N_GROUPS * DIM + NBINS * CNT_PAD + 16) * sizeof(unsigned), stream);

    foldhist_kernel<<<6 + HIST_BLOCKS, 256, 0, stream>>>(
        lin_W, lin_b, lin_gamma, lin_beta, lin_mean, lin_var,
        conv_W, conv_b, conv_gamma, conv_beta, conv_mean, conv_var,
        shf, Wfb, x0b, xbufb, dst, blockcnt);

    colsum_scan_kernel<<<CS_BLOCKS, 256, 0, stream>>>(blockcnt, bincnt,
                                                      binoff, bincur, donec);

    scatter_linz_kernel<<<SCAT_BLOCKS + GF2_BLOCKS, 512, 0, stream>>>(
        src, dst, bincur, binbuf, blockcnt,
        x0, x0b, Wfb, shf, batch, lw, Z, segmx);

    binsort_kernel<<<NBINS, 256, 0, stream>>>(binbuf, binoff, esrc, nodeptr);

    // ---- layer 1 ----
    gin_fused_kernel<<<gf_blocks, 256, 0, stream>>>(x0b, esrc, nodeptr,
                                                    Wfb + 3 * DIM * DIM, shf + 3 * DIM,
                                                    Wfb + 1 * DIM * DIM, shf + 1 * DIM,
                                                    batch, lw + 1,
                                                    xbufb, (float*)nullptr, Z,
                                                    segmx + N_GROUPS * DIM);

    // ---- layer 2 ----
    gin_fused_kernel<<<gf_blocks, 256, 0, stream>>>(xbufb, esrc, nodeptr,
                                                    Wfb + 4 * DIM * DIM, shf + 4 * DIM,
                                                    Wfb + 2 * DIM * DIM, shf + 2 * DIM,
                                                    batch, lw + 2,
                                                    (unsigned short*)nullptr, xout, Z,
                                                    segmx + 2 * N_GROUPS * DIM);

    add_out3_kernel<<<8, 256, 0, stream>>>(segmx, segmx + N_GROUPS * DIM,
                                           segmx + 2 * N_GROUPS * DIM, out);
}